// Round 1
// 660.291 us; speedup vs baseline: 1.0143x; 1.0143x over previous
//
#include <hip/hip_runtime.h>

#define B 256
#define P 64
#define R 8
#define V 32000
#define W 1000        // v-tile width (32 tiles exactly cover V=32000)
#define NT 32
#define SPLIT 4
#define CHUNK 8

#define FMA4(a, s, e) { (a).x = fmaf((s),(e).x,(a).x); (a).y = fmaf((s),(e).y,(a).y); \
                        (a).z = fmaf((s),(e).z,(a).z); (a).w = fmaf((s),(e).w,(a).w); }

// Per-(example, v-tile) partial sums of exp(logit). Each slot is written by
// exactly one (r, split) block per run (deterministic ownership), so no
// zeroing and no atomics are needed. Device-global: no workspace dependency.
__device__ float S_part_g[B * NT];

// Kernel A: logits[b,v] = bg[r,v] + author[m,r,v] + sum_p z[b,p]*pers[p,r,v],
// mask-filled, AND per-(b,tile) partial sum of exp(logit) (max-free: logits
// are bounded ~[-1.5, 1.5] for live entries; masked -> exp(-100) == 0).
__global__ __launch_bounds__(256) void logits_kernel(
    const int*   __restrict__ m_idx,
    const float* __restrict__ z,           // B x P
    const int*   __restrict__ r_idx,
    const int*   __restrict__ role_mask,   // R x V
    const float* __restrict__ eta_bg,      // R x V
    const float* __restrict__ eta_author,  // M x R x V
    const float* __restrict__ eta_pers,    // P x R x V
    float*       __restrict__ out)         // B x V
{
    const int tile = blockIdx.x;
    const int r    = blockIdx.y;
    const int sp   = blockIdx.z;
    const int t    = threadIdx.x;
    const int v0   = tile * W;

    __shared__ int list[B];
    __shared__ unsigned long long wmask[4];
    __shared__ __align__(16) float zsh[P][CHUNK];   // zsh[p][j]
    __shared__ float red[4][CHUNK];                 // per-wave exp-sum partials

    // Deterministic list build: pos[b] = #{b' < b : r_idx[b'] == r}.
    // Every block (all sp splits) gets the SAME ordering, so the union of
    // position classes {sp, sp+4, ...} covers each example exactly once.
    const bool match = (t < B) && (r_idx[t] == r);
    unsigned long long bal = __ballot(match);
    const int wave = t >> 6, lane = t & 63;
    if (lane == 0) wmask[wave] = bal;
    __syncthreads();
    int base = 0;
    #pragma unroll
    for (int w2 = 0; w2 < 4; ++w2) if (w2 < wave) base += __popcll(wmask[w2]);
    if (match) {
        int pos = base + __popcll(bal & ((1ull << lane) - 1ull));
        list[pos] = t;
    }
    int n = 0;
    #pragma unroll
    for (int w2 = 0; w2 < 4; ++w2) n += __popcll(wmask[w2]);
    __syncthreads();

    const bool active = (t < 250);      // 250 threads * 4 v = 1000 = W
    const int vt = v0 + 4 * t;

    float4 bgv = make_float4(0.f, 0.f, 0.f, 0.f);
    int4 mk = make_int4(1, 1, 1, 1);
    if (active) {
        bgv = *(const float4*)(eta_bg + (size_t)r * V + vt);
        mk  = *(const int4*)(role_mask + (size_t)r * V + vt);
    }

    // this split handles list positions sp, sp+SPLIT, sp+2*SPLIT, ...
    int nsub = (n > sp) ? (n - sp + SPLIT - 1) / SPLIT : 0;

    for (int c0 = 0; c0 < nsub; c0 += CHUNK) {
        const int nb = min(CHUNK, nsub - c0);
        __syncthreads();   // protect zsh/red before restage
        // stage z for this chunk's examples: zsh[p][j] = z[b_j, p]
        for (int idx = t; idx < P * CHUNK; idx += 256) {
            int p = idx & (P - 1);
            int j = idx >> 6;
            float val = 0.f;
            if (j < nb) {
                int b = list[sp + SPLIT * (c0 + j)];
                val = z[b * P + p];
            }
            zsh[p][j] = val;
        }
        __syncthreads();

        float es[CHUNK];
        #pragma unroll
        for (int j = 0; j < CHUNK; ++j) es[j] = 0.f;

        if (active) {
            float4 acc[CHUNK];
            #pragma unroll
            for (int j = 0; j < CHUNK; ++j) acc[j] = make_float4(0.f, 0.f, 0.f, 0.f);

            const float* ep = eta_pers + (size_t)r * V + vt;
            #pragma unroll 4
            for (int p = 0; p < P; ++p) {
                float4 e  = *(const float4*)(ep + (size_t)p * (R * V));
                float4 za = *(const float4*)&zsh[p][0];
                float4 zb = *(const float4*)&zsh[p][4];
                FMA4(acc[0], za.x, e); FMA4(acc[1], za.y, e);
                FMA4(acc[2], za.z, e); FMA4(acc[3], za.w, e);
                FMA4(acc[4], zb.x, e); FMA4(acc[5], zb.y, e);
                FMA4(acc[6], zb.z, e); FMA4(acc[7], zb.w, e);
            }

            // epilogue: add bg + author, mask-fill, store, exp-accumulate
            for (int j = 0; j < nb; ++j) {
                int b = list[sp + SPLIT * (c0 + j)];
                int m = m_idx[b];
                float4 au = *(const float4*)(eta_author + ((size_t)m * R + r) * V + vt);
                float4 o;
                o.x = (mk.x == 0) ? -100.f : acc[j].x + bgv.x + au.x;
                o.y = (mk.y == 0) ? -100.f : acc[j].y + bgv.y + au.y;
                o.z = (mk.z == 0) ? -100.f : acc[j].z + bgv.z + au.z;
                o.w = (mk.w == 0) ? -100.f : acc[j].w + bgv.w + au.w;
                *(float4*)(out + (size_t)b * V + vt) = o;
                es[j] = __expf(o.x) + __expf(o.y) + __expf(o.z) + __expf(o.w);
            }
        }

        // block-wide reduction of es[j] -> S_part_g[b, tile]
        #pragma unroll
        for (int j = 0; j < CHUNK; ++j) {
            float v = es[j];
            #pragma unroll
            for (int off = 32; off > 0; off >>= 1) v += __shfl_down(v, off);
            if (lane == 0) red[wave][j] = v;
        }
        __syncthreads();
        if (t < CHUNK && t < nb) {
            int b = list[sp + SPLIT * (c0 + t)];
            S_part_g[b * NT + tile] = red[0][t] + red[1][t] + red[2][t] + red[3][t];
        }
    }
}

// Kernel B: single streaming pass — lse[b] = log(sum of 32 partials);
// out[b,v] -= lse. Grid (B, 4): 1024 blocks = 4/CU.
__global__ __launch_bounds__(256) void finalize_kernel(float* __restrict__ out)
{
    const int b = blockIdx.x;
    const int q = blockIdx.y;
    const int t = threadIdx.x;

    __shared__ float lse_sh;
    if (t < 32) {
        float v = S_part_g[b * NT + t];
        #pragma unroll
        for (int off = 16; off > 0; off >>= 1) v += __shfl_down(v, off, 32);
        if (t == 0) lse_sh = __logf(v);
    }
    __syncthreads();
    const float lse = lse_sh;

    float* rowq = out + (size_t)b * V + q * (V / 4);   // 8000 floats per quarter
    for (int i = t; i < V / 16; i += 256) {            // 2000 float4 per quarter
        float4 x = *(const float4*)(rowq + 4 * i);
        x.x -= lse; x.y -= lse; x.z -= lse; x.w -= lse;
        *(float4*)(rowq + 4 * i) = x;
    }
}

extern "C" void kernel_launch(void* const* d_in, const int* in_sizes, int n_in,
                              void* d_out, int out_size, void* d_ws, size_t ws_size,
                              hipStream_t stream) {
    const int*   m_idx  = (const int*)d_in[0];
    const float* z      = (const float*)d_in[1];
    const int*   r_idx  = (const int*)d_in[2];
    const int*   mask   = (const int*)d_in[3];
    const float* bg     = (const float*)d_in[4];
    const float* author = (const float*)d_in[5];
    const float* pers   = (const float*)d_in[6];
    float* out = (float*)d_out;

    logits_kernel<<<dim3(NT, R, SPLIT), 256, 0, stream>>>(
        m_idx, z, r_idx, mask, bg, author, pers, out);
    finalize_kernel<<<dim3(B, 4), 256, 0, stream>>>(out);
}